// Round 6
// baseline (745.491 us; speedup 1.0000x reference)
//
#include <hip/hip_runtime.h>
#include <hip/hip_bf16.h>

#define BS 32
#define QL 16
#define KV 2048
#define NH 16
#define DK 128
#define DM 2048
#define MROWS (BS*QL)   // 512
#define KCA 8           // kernel-A k-chunks (256 rows each)
#define AROWS (KV/KCA)
#define KCB 4           // kernel-B k-chunks (512 rows each)
#define BROWS (KV/KCB)
#define SPLICE (KV-QL)  // 2032

#define SCALE 0.08838834764831845f  // 1/sqrt(128)
#define LOG2E 1.4426950408889634f

typedef __bf16 bf16x8 __attribute__((ext_vector_type(8)));
typedef float f32x4 __attribute__((ext_vector_type(4)));
typedef unsigned short us8 __attribute__((ext_vector_type(8)));
typedef unsigned short us4 __attribute__((ext_vector_type(4)));

__device__ inline unsigned short f2bf(float f){
    unsigned u = __builtin_bit_cast(unsigned, f);
    u += 0x7fffu + ((u >> 16) & 1u);
    return (unsigned short)(u >> 16);
}
__device__ inline float bf2f(unsigned short u){
    unsigned x = ((unsigned)u) << 16;
    return __builtin_bit_cast(float, x);
}

// C[m][n] = sum_k (A0+A1+A2+A3)[m][k] * W[n][k] + bias[n]   (A1..A3 nullable)
__global__ __launch_bounds__(256) void gemm_bt(
    const float* __restrict__ A0p, const float* __restrict__ A1p,
    const float* __restrict__ A2p, const float* __restrict__ A3p,
    const float* __restrict__ W0, const float* __restrict__ W1, const float* __restrict__ W2,
    const float* __restrict__ b0, const float* __restrict__ b1, const float* __restrict__ b2,
    float* __restrict__ C0, float* __restrict__ C1, float* __restrict__ C2,
    int spliceMask)
{
    int z = blockIdx.z;
    const float* W    = (z==0)?W0:(z==1)?W1:W2;
    const float* bias = (z==0)?b0:(z==1)?b1:b2;
    float*       C    = (z==0)?C0:(z==1)?C1:C2;
    int spl = (spliceMask >> z) & 1;

    const int K = DM, N = DM;
    int mBase = blockIdx.x * 64, nBase = blockIdx.y * 64;

    __shared__ __align__(16) unsigned short As[64*40];
    __shared__ __align__(16) unsigned short Bs[64*40];

    int t = threadIdx.x;
    int wv = t >> 6, lane = t & 63;
    int row = t >> 2, seg = (t & 3) * 8;
    int g = lane >> 4, c = lane & 15;

    f32x4 acc[4] = {{0,0,0,0},{0,0,0,0},{0,0,0,0},{0,0,0,0}};

    for (int k0 = 0; k0 < K; k0 += 32) {
        __syncthreads();
        {
            size_t off = (size_t)(mBase + row) * K + k0 + seg;
            float4 a0 = *(const float4*)(A0p + off), a1 = *(const float4*)(A0p + off + 4);
            if (A1p) {
                float4 c0 = *(const float4*)(A1p + off), c1 = *(const float4*)(A1p + off + 4);
                a0.x+=c0.x; a0.y+=c0.y; a0.z+=c0.z; a0.w+=c0.w;
                a1.x+=c1.x; a1.y+=c1.y; a1.z+=c1.z; a1.w+=c1.w;
            }
            if (A2p) {
                float4 c0 = *(const float4*)(A2p + off), c1 = *(const float4*)(A2p + off + 4);
                a0.x+=c0.x; a0.y+=c0.y; a0.z+=c0.z; a0.w+=c0.w;
                a1.x+=c1.x; a1.y+=c1.y; a1.z+=c1.z; a1.w+=c1.w;
            }
            if (A3p) {
                float4 c0 = *(const float4*)(A3p + off), c1 = *(const float4*)(A3p + off + 4);
                a0.x+=c0.x; a0.y+=c0.y; a0.z+=c0.z; a0.w+=c0.w;
                a1.x+=c1.x; a1.y+=c1.y; a1.z+=c1.z; a1.w+=c1.w;
            }
            us8 av = { f2bf(a0.x), f2bf(a0.y), f2bf(a0.z), f2bf(a0.w),
                       f2bf(a1.x), f2bf(a1.y), f2bf(a1.z), f2bf(a1.w) };
            *(us8*)&As[row*40 + seg] = av;
        }
        {
            const float* wp = W + (size_t)(nBase + row) * K + k0 + seg;
            float4 w0v = *(const float4*)wp, w1v = *(const float4*)(wp + 4);
            us8 wv8 = { f2bf(w0v.x), f2bf(w0v.y), f2bf(w0v.z), f2bf(w0v.w),
                        f2bf(w1v.x), f2bf(w1v.y), f2bf(w1v.z), f2bf(w1v.w) };
            *(us8*)&Bs[row*40 + seg] = wv8;
        }
        __syncthreads();

        bf16x8 af = __builtin_bit_cast(bf16x8, *(us8*)&As[(wv*16 + c)*40 + g*8]);
        #pragma unroll
        for (int j = 0; j < 4; j++) {
            bf16x8 bf = __builtin_bit_cast(bf16x8, *(us8*)&Bs[(j*16 + c)*40 + g*8]);
            acc[j] = __builtin_amdgcn_mfma_f32_16x16x32_bf16(af, bf, acc[j], 0, 0, 0);
        }
    }

    #pragma unroll
    for (int j = 0; j < 4; j++) {
        int n = nBase + j*16 + c;
        float bb = bias[n];
        #pragma unroll
        for (int r = 0; r < 4; r++) {
            int m = mBase + wv*16 + g*4 + r;
            size_t rowoff = spl ? ((size_t)(m >> 4) * KV + SPLICE + (m & 15)) * (size_t)N
                                : (size_t)m * (size_t)N;
            C[rowoff + n] = acc[j][r] + bb;
        }
    }
}

// A: K-copy + QK^T via LDS-staged tiles with contiguous global access.
// grid (4 head-groups, BS, KCA), 256 threads (4 waves; wave = one head).
// Per 32-row tile: stage K[rows][hg*512..+512] fp32->bf16 into swizzled LDS,
// stream the same data to kout, then MFMA per wave. Scores -> bf16 S + stats.
__global__ __launch_bounds__(256) void kcopy_scores(
    const float* __restrict__ qws, const float* __restrict__ kcache,
    const int* __restrict__ mask,
    float* __restrict__ kout, __hip_bfloat16* __restrict__ Sbuf,
    float* __restrict__ statsM, float* __restrict__ statsL)
{
    int hg = blockIdx.x, b = blockIdx.y, kc = blockIdx.z;
    int t = threadIdx.x, wv = t >> 6, lane = t & 63;
    int g = lane >> 4, c = lane & 15;
    int h = hg*4 + wv;
    size_t bKV = (size_t)b * KV;
    size_t bh  = (size_t)b * NH + h;
    unsigned short* S = (unsigned short*)Sbuf;

    __shared__ __align__(16) unsigned short Kl[32*512];  // 32 KB, XOR-swizzled

    // Q A-fragments for this wave's head (scaled, bf16)
    bf16x8 af[4];
    {
        const float* qp = qws + (size_t)(b*QL + c) * DM + h*DK + g*8;
        #pragma unroll
        for (int ks = 0; ks < 4; ks++) {
            float4 q0 = *(const float4*)(qp + ks*32);
            float4 q1 = *(const float4*)(qp + ks*32 + 4);
            us8 qv = { f2bf(q0.x*SCALE), f2bf(q0.y*SCALE), f2bf(q0.z*SCALE), f2bf(q0.w*SCALE),
                       f2bf(q1.x*SCALE), f2bf(q1.y*SCALE), f2bf(q1.z*SCALE), f2bf(q1.w*SCALE) };
            af[ks] = __builtin_bit_cast(bf16x8, qv);
        }
    }

    float mloc[4] = {-1e30f,-1e30f,-1e30f,-1e30f};
    float lloc[4] = {0.f,0.f,0.f,0.f};

    for (int tile = 0; tile < AROWS/32; ++tile) {
        int row0 = kc*AROWS + tile*32;
        __syncthreads();
        // stage 32 rows x 512 dims (contiguous 2KB per row) + copy-out
        #pragma unroll
        for (int p = 0; p < 16; p++) {
            int f = p*256 + t;           // float4 index in tile
            int r = f >> 7;              // 0..31
            int d4 = (f & 127) * 4;      // 0..508
            int grow = row0 + r;
            size_t off = (bKV + grow)*DM + hg*512 + d4;
            const float* src = (grow >= SPLICE ? kout : kcache) + off;
            float4 v = *(const float4*)src;
            if (grow < SPLICE) *(float4*)(kout + off) = v;
            int e = (r*512 + d4) ^ ((r & 7) << 3);
            us4 bv = { f2bf(v.x), f2bf(v.y), f2bf(v.z), f2bf(v.w) };
            *(us4*)&Kl[e] = bv;
        }
        __syncthreads();

        #pragma unroll
        for (int sub = 0; sub < 2; ++sub) {
            int r = sub*16 + c;
            f32x4 sc = {0,0,0,0};
            #pragma unroll
            for (int ks = 0; ks < 4; ks++) {
                int e = (r*512 + wv*128 + ks*32 + g*8) ^ ((r & 7) << 3);
                sc = __builtin_amdgcn_mfma_f32_16x16x32_bf16(af[ks],
                        __builtin_bit_cast(bf16x8, *(us8*)&Kl[e]), sc, 0, 0, 0);
            }
            int krow = row0 + sub*16 + c;
            const int* mrow = mask + (size_t)b * QL * KV + krow;
            us4 sv;
            #pragma unroll
            for (int rr = 0; rr < 4; rr++) {
                int q = g*4 + rr;
                float s = sc[rr];
                if (mrow[(size_t)q * KV] == 0) s = -1e9f;
                unsigned short u = f2bf(s);
                sv[rr] = u;
                float sb = bf2f(u);
                float nm = fmaxf(mloc[rr], sb);
                lloc[rr] = lloc[rr]*exp2f((mloc[rr]-nm)*LOG2E) + exp2f((sb-nm)*LOG2E);
                mloc[rr] = nm;
            }
            *(us4*)(void*)&S[(bh*KV + krow)*QL + g*4] = sv;
        }
    }

    // reduce stats over the 16 c-lanes (per wave = per head)
    #pragma unroll
    for (int rr = 0; rr < 4; rr++) {
        float m = mloc[rr], l = lloc[rr];
        #pragma unroll
        for (int mm = 1; mm < 16; mm <<= 1) {
            float mo = __shfl_xor(m, mm), lo = __shfl_xor(l, mm);
            float nm = fmaxf(m, mo);
            l = l*exp2f((m-nm)*LOG2E) + lo*exp2f((mo-nm)*LOG2E);
            m = nm;
        }
        if (c == 0) {
            statsM[(bh*KCA + kc)*QL + g*4 + rr] = m;
            statsL[(bh*KCA + kc)*QL + g*4 + rr] = l;
        }
    }
}

// B: V-copy + PV via LDS-staged tiles with contiguous global access.
// grid (4 dim-groups, BS, KCB), 256 threads (4 waves; wave = one head).
// Per 32-row tile: stage P (exact softmax numerators) and V; accumulate O.
__global__ __launch_bounds__(256) void vcopy_pv(
    const float* __restrict__ vcache, const __hip_bfloat16* __restrict__ Sbuf,
    const float* __restrict__ statsM, const float* __restrict__ statsL,
    float* __restrict__ vout, float* __restrict__ awsP)
{
    int dg = blockIdx.x, b = blockIdx.y, kc = blockIdx.z;
    int t = threadIdx.x, wv = t >> 6, lane = t & 63;
    int h = dg*4 + wv;
    size_t bKV = (size_t)b * KV;
    size_t bh  = (size_t)b * NH + h;
    const unsigned short* S = (const unsigned short*)Sbuf;

    __shared__ __align__(16) unsigned short Vl[32*512];  // 32 KB, XOR-swizzled
    __shared__ float Pl[4][32][17];                      // ~8.7 KB
    __shared__ float sM[4][16], sLinv[4][16];

    if (t < 64) {
        int hh = t >> 4, q = t & 15;
        size_t bhh = (size_t)b*NH + dg*4 + hh;
        float M = -1e30f;
        #pragma unroll
        for (int c8 = 0; c8 < KCA; c8++)
            M = fmaxf(M, statsM[(bhh*KCA + c8)*QL + q]);
        float L = 0.f;
        #pragma unroll
        for (int c8 = 0; c8 < KCA; c8++)
            L += statsL[(bhh*KCA + c8)*QL + q] * exp2f((statsM[(bhh*KCA + c8)*QL + q] - M)*LOG2E);
        sM[hh][q] = M; sLinv[hh][q] = 1.0f / L;
    }
    __syncthreads();

    int q = lane >> 2, dq = lane & 3;
    float O[32];
    #pragma unroll
    for (int i = 0; i < 32; i++) O[i] = 0.f;

    for (int tile = 0; tile < BROWS/32; ++tile) {
        int row0 = kc*BROWS + tile*32;
        __syncthreads();
        // stage P = exp(S - M) for this wave's head: 32 k x 16 q
        {
            int idx = t & 63;
            int k = idx >> 1, q0 = (idx & 1) * 8;
            int krow = row0 + k;
            us8 sv = *(const us8*)(const void*)&S[(bh*KV + krow)*QL + q0];
            #pragma unroll
            for (int j = 0; j < 8; j++)
                Pl[wv][k][q0 + j] = exp2f((bf2f(sv[j]) - sM[wv][q0 + j])*LOG2E);
        }
        // stage 32 rows x 512 dims of V + copy-out
        #pragma unroll
        for (int p = 0; p < 16; p++) {
            int f = p*256 + t;
            int r = f >> 7;
            int d4 = (f & 127) * 4;
            int grow = row0 + r;
            size_t off = (bKV + grow)*DM + dg*512 + d4;
            const float* src = (grow >= SPLICE ? vout : vcache) + off;
            float4 v = *(const float4*)src;
            if (grow < SPLICE) *(float4*)(vout + off) = v;
            int e = (r*512 + d4) ^ ((r & 7) << 3);
            us4 bv = { f2bf(v.x), f2bf(v.y), f2bf(v.z), f2bf(v.w) };
            *(us4*)&Vl[e] = bv;
        }
        __syncthreads();
        // O += P * V
        for (int k = 0; k < 32; k++) {
            float p = Pl[wv][k][q];
            #pragma unroll
            for (int j = 0; j < 4; j++) {
                int e = (k*512 + wv*128 + dq*32 + j*8) ^ ((k & 7) << 3);
                us8 v8 = *(const us8*)&Vl[e];
                O[j*8+0] += p*bf2f(v8[0]); O[j*8+1] += p*bf2f(v8[1]);
                O[j*8+2] += p*bf2f(v8[2]); O[j*8+3] += p*bf2f(v8[3]);
                O[j*8+4] += p*bf2f(v8[4]); O[j*8+5] += p*bf2f(v8[5]);
                O[j*8+6] += p*bf2f(v8[6]); O[j*8+7] += p*bf2f(v8[7]);
            }
        }
    }

    float inv = sLinv[wv][q];
    float* op = awsP + (size_t)kc * MROWS * DM
              + (size_t)(b*QL + q)*DM + dg*512 + wv*128 + dq*32;
    #pragma unroll
    for (int j = 0; j < 4; j++) {
        float4 o0 = {O[j*8+0]*inv, O[j*8+1]*inv, O[j*8+2]*inv, O[j*8+3]*inv};
        float4 o1 = {O[j*8+4]*inv, O[j*8+5]*inv, O[j*8+6]*inv, O[j*8+7]*inv};
        *(float4*)(op + j*8)     = o0;
        *(float4*)(op + j*8 + 4) = o1;
    }
}

extern "C" void kernel_launch(void* const* d_in, const int* in_sizes, int n_in,
                              void* d_out, int out_size, void* d_ws, size_t ws_size,
                              hipStream_t stream)
{
    (void)in_sizes; (void)n_in; (void)out_size; (void)ws_size;

    const float* x      = (const float*)d_in[0];
    const float* kcache = (const float*)d_in[1];
    const float* vcache = (const float*)d_in[2];
    const int*   mask   = (const int*)  d_in[3];
    const float* Wq     = (const float*)d_in[4];
    const float* bq     = (const float*)d_in[5];
    const float* Wk     = (const float*)d_in[6];
    const float* bk     = (const float*)d_in[7];
    const float* Wv     = (const float*)d_in[8];
    const float* bv     = (const float*)d_in[9];
    const float* Wo     = (const float*)d_in[10];
    const float* bo     = (const float*)d_in[11];

    float* out  = (float*)d_out;
    float* kout = out  + (size_t)MROWS * DM;
    float* vout = kout + (size_t)BS * KV * DM;

    float* qws    = (float*)d_ws;                           // 4 MB
    float* awsP   = qws  + (size_t)MROWS * DM;              // 4 x 4 MB partials
    float* statsM = awsP + (size_t)KCB * MROWS * DM;        // 256 KB
    float* statsL = statsM + (size_t)BS * NH * KCA * QL;    // 256 KB
    __hip_bfloat16* Sbuf = (__hip_bfloat16*)(statsL + (size_t)BS * NH * KCA * QL); // 32 MB

    // 1) QKV projections; K/V rows splice directly into cache outputs
    dim3 gq(MROWS/64, DM/64, 3);
    gemm_bt<<<gq, 256, 0, stream>>>(x, nullptr, nullptr, nullptr,
                                    Wq, Wk, Wv, bq, bk, bv,
                                    qws, kout, vout, 0b110);

    // 2) K-copy + scores + stats
    dim3 ga(4, BS, KCA);
    kcopy_scores<<<ga, 256, 0, stream>>>(qws, kcache, mask, kout, Sbuf, statsM, statsL);

    // 3) V-copy + PV partials (kc selects partial buffer inside)
    dim3 gb(4, BS, KCB);
    vcopy_pv<<<gb, 256, 0, stream>>>(vcache, Sbuf, statsM, statsL, vout, awsP);

    // 4) output projection, summing the four PV partial buffers
    float* a0 = awsP;
    float* a1 = awsP + 1*(size_t)MROWS*DM;
    float* a2 = awsP + 2*(size_t)MROWS*DM;
    float* a3 = awsP + 3*(size_t)MROWS*DM;
    dim3 go(MROWS/64, DM/64, 1);
    gemm_bt<<<go, 256, 0, stream>>>(a0, a1, a2, a3,
                                    Wo, Wo, Wo, bo, bo, bo,
                                    out, out, out, 0);
}

// Round 7
// 688.552 us; speedup vs baseline: 1.0827x; 1.0827x over previous
//
#include <hip/hip_runtime.h>
#include <hip/hip_bf16.h>

#define BS 32
#define QL 16
#define KV 2048
#define NH 16
#define DK 128
#define DM 2048
#define MROWS (BS*QL)   // 512
#define KCA 4           // kernel-A k-chunks (512 rows each)
#define AROWS (KV/KCA)
#define KCB 2           // kernel-B k-chunks (1024 rows each)
#define BROWS (KV/KCB)
#define SPLICE (KV-QL)  // 2032

#define SCALE 0.08838834764831845f  // 1/sqrt(128)
#define LOG2E 1.4426950408889634f

typedef __bf16 bf16x8 __attribute__((ext_vector_type(8)));
typedef float f32x4 __attribute__((ext_vector_type(4)));
typedef unsigned short us8 __attribute__((ext_vector_type(8)));
typedef unsigned short us4 __attribute__((ext_vector_type(4)));

__device__ inline unsigned short f2bf(float f){
    unsigned u = __builtin_bit_cast(unsigned, f);
    u += 0x7fffu + ((u >> 16) & 1u);
    return (unsigned short)(u >> 16);
}
__device__ inline float bf2f(unsigned short u){
    unsigned x = ((unsigned)u) << 16;
    return __builtin_bit_cast(float, x);
}

// C[m][n] = sum_k (A0(+A1))[m][k] * W[n][k] + bias[n], 128x128 tiles.
// grid (N/128, M/128, z) — N fastest so same-A blocks are id-consecutive.
__global__ __launch_bounds__(256) void gemm128(
    const float* __restrict__ A0p, const float* __restrict__ A1p,
    const float* __restrict__ W0, const float* __restrict__ W1, const float* __restrict__ W2,
    const float* __restrict__ b0, const float* __restrict__ b1, const float* __restrict__ b2,
    float* __restrict__ C0, float* __restrict__ C1, float* __restrict__ C2,
    int spliceMask)
{
    int z = blockIdx.z;
    const float* W    = (z==0)?W0:(z==1)?W1:W2;
    const float* bias = (z==0)?b0:(z==1)?b1:b2;
    float*       C    = (z==0)?C0:(z==1)?C1:C2;
    int spl = (spliceMask >> z) & 1;

    const int K = DM, N = DM;
    int nBase = blockIdx.x * 128, mBase = blockIdx.y * 128;

    __shared__ __align__(16) unsigned short As[128*40];
    __shared__ __align__(16) unsigned short Bs[128*40];

    int t = threadIdx.x;
    int wv = t >> 6, lane = t & 63;
    int g = lane >> 4, c = lane & 15;
    int wm = wv >> 1, wn = wv & 1;
    int srow = t >> 1, shalf = (t & 1) * 16;

    f32x4 acc[4][4];
    #pragma unroll
    for (int i = 0; i < 4; i++)
        #pragma unroll
        for (int j = 0; j < 4; j++) acc[i][j] = (f32x4){0,0,0,0};

    for (int k0 = 0; k0 < K; k0 += 32) {
        __syncthreads();
        {   // stage A: 128 rows x 32 k, 16 floats per thread
            size_t off = (size_t)(mBase + srow) * K + k0 + shalf;
            float4 a0 = *(const float4*)(A0p + off);
            float4 a1 = *(const float4*)(A0p + off + 4);
            float4 a2 = *(const float4*)(A0p + off + 8);
            float4 a3 = *(const float4*)(A0p + off + 12);
            if (A1p) {
                float4 c0 = *(const float4*)(A1p + off);
                float4 c1 = *(const float4*)(A1p + off + 4);
                float4 c2 = *(const float4*)(A1p + off + 8);
                float4 c3 = *(const float4*)(A1p + off + 12);
                a0.x+=c0.x; a0.y+=c0.y; a0.z+=c0.z; a0.w+=c0.w;
                a1.x+=c1.x; a1.y+=c1.y; a1.z+=c1.z; a1.w+=c1.w;
                a2.x+=c2.x; a2.y+=c2.y; a2.z+=c2.z; a2.w+=c2.w;
                a3.x+=c3.x; a3.y+=c3.y; a3.z+=c3.z; a3.w+=c3.w;
            }
            us8 p0 = { f2bf(a0.x), f2bf(a0.y), f2bf(a0.z), f2bf(a0.w),
                       f2bf(a1.x), f2bf(a1.y), f2bf(a1.z), f2bf(a1.w) };
            us8 p1 = { f2bf(a2.x), f2bf(a2.y), f2bf(a2.z), f2bf(a2.w),
                       f2bf(a3.x), f2bf(a3.y), f2bf(a3.z), f2bf(a3.w) };
            *(us8*)&As[srow*40 + shalf]     = p0;
            *(us8*)&As[srow*40 + shalf + 8] = p1;
        }
        {   // stage B from W rows
            size_t off = (size_t)(nBase + srow) * K + k0 + shalf;
            float4 a0 = *(const float4*)(W + off);
            float4 a1 = *(const float4*)(W + off + 4);
            float4 a2 = *(const float4*)(W + off + 8);
            float4 a3 = *(const float4*)(W + off + 12);
            us8 p0 = { f2bf(a0.x), f2bf(a0.y), f2bf(a0.z), f2bf(a0.w),
                       f2bf(a1.x), f2bf(a1.y), f2bf(a1.z), f2bf(a1.w) };
            us8 p1 = { f2bf(a2.x), f2bf(a2.y), f2bf(a2.z), f2bf(a2.w),
                       f2bf(a3.x), f2bf(a3.y), f2bf(a3.z), f2bf(a3.w) };
            *(us8*)&Bs[srow*40 + shalf]     = p0;
            *(us8*)&Bs[srow*40 + shalf + 8] = p1;
        }
        __syncthreads();

        bf16x8 af[4], bfr[4];
        #pragma unroll
        for (int i = 0; i < 4; i++)
            af[i] = __builtin_bit_cast(bf16x8, *(us8*)&As[(wm*64 + i*16 + c)*40 + g*8]);
        #pragma unroll
        for (int j = 0; j < 4; j++)
            bfr[j] = __builtin_bit_cast(bf16x8, *(us8*)&Bs[(wn*64 + j*16 + c)*40 + g*8]);
        #pragma unroll
        for (int i = 0; i < 4; i++)
            #pragma unroll
            for (int j = 0; j < 4; j++)
                acc[i][j] = __builtin_amdgcn_mfma_f32_16x16x32_bf16(af[i], bfr[j], acc[i][j], 0, 0, 0);
    }

    #pragma unroll
    for (int j = 0; j < 4; j++) {
        int n = nBase + wn*64 + j*16 + c;
        float bb = bias[n];
        #pragma unroll
        for (int i = 0; i < 4; i++) {
            #pragma unroll
            for (int r = 0; r < 4; r++) {
                int m = mBase + wm*64 + i*16 + g*4 + r;
                size_t rowoff = spl ? ((size_t)(m >> 4) * KV + SPLICE + (m & 15)) * (size_t)N
                                    : (size_t)m * (size_t)N;
                C[rowoff + n] = acc[i][j][r] + bb;
            }
        }
    }
}

// A: K-copy fused with QK^T; max-free softmax: stores P = exp(s) bf16 + l sums.
// grid (NH, BS, KCA), 256 threads (4 waves, 8 tiles of 16 rows each).
__global__ __launch_bounds__(256) void kcopy_p(
    const float* __restrict__ qws, const float* __restrict__ kcache,
    const int* __restrict__ mask,
    float* __restrict__ kout, __hip_bfloat16* __restrict__ Pbuf,
    float* __restrict__ statsL)
{
    int h = blockIdx.x, b = blockIdx.y, kc = blockIdx.z;
    int t = threadIdx.x, wv = t >> 6, lane = t & 63;
    int g = lane >> 4, c = lane & 15;
    size_t bKV = (size_t)b * KV;
    size_t bh  = (size_t)b * NH + h;
    unsigned short* P = (unsigned short*)Pbuf;

    __shared__ float smL[4][16];

    // Q A-fragments for head h (scaled, bf16); constant over the loop
    bf16x8 af[4];
    {
        const float* qp = qws + (size_t)(b*QL + c) * DM + h*DK + g*8;
        #pragma unroll
        for (int ks = 0; ks < 4; ks++) {
            float4 q0 = *(const float4*)(qp + ks*32);
            float4 q1 = *(const float4*)(qp + ks*32 + 4);
            us8 qv = { f2bf(q0.x*SCALE), f2bf(q0.y*SCALE), f2bf(q0.z*SCALE), f2bf(q0.w*SCALE),
                       f2bf(q1.x*SCALE), f2bf(q1.y*SCALE), f2bf(q1.z*SCALE), f2bf(q1.w*SCALE) };
            af[ks] = __builtin_bit_cast(bf16x8, qv);
        }
    }

    float lloc[4] = {0.f,0.f,0.f,0.f};

    for (int i = 0; i < 8; i++) {
        int n0 = kc*AROWS + (i*4 + wv)*16;
        int krow = n0 + c;
        bool spl = (n0 >= SPLICE);   // tile-uniform: only the last tile
        const float* src = (spl ? kout : kcache) + (bKV + krow)*DM + h*DK + g*8;

        float4 kvv[8];
        #pragma unroll
        for (int ks = 0; ks < 4; ks++) {
            kvv[2*ks]   = *(const float4*)(src + ks*32);
            kvv[2*ks+1] = *(const float4*)(src + ks*32 + 4);
        }
        if (!spl) {
            float* dst = kout + (bKV + krow)*DM + h*DK + g*8;
            #pragma unroll
            for (int ks = 0; ks < 4; ks++) {
                *(float4*)(dst + ks*32)     = kvv[2*ks];
                *(float4*)(dst + ks*32 + 4) = kvv[2*ks+1];
            }
        }
        f32x4 sc = {0,0,0,0};
        #pragma unroll
        for (int ks = 0; ks < 4; ks++) {
            float4 k0 = kvv[2*ks], k1 = kvv[2*ks+1];
            us8 kb = { f2bf(k0.x), f2bf(k0.y), f2bf(k0.z), f2bf(k0.w),
                       f2bf(k1.x), f2bf(k1.y), f2bf(k1.z), f2bf(k1.w) };
            sc = __builtin_amdgcn_mfma_f32_16x16x32_bf16(af[ks],
                    __builtin_bit_cast(bf16x8, kb), sc, 0, 0, 0);
        }
        // max-free: p = exp(s) (or 0 if masked); accumulate l; store P bf16
        const int* mrow = mask + (size_t)b * QL * KV + krow;
        us4 pv4;
        #pragma unroll
        for (int r = 0; r < 4; r++) {
            int q = g*4 + r;
            float p = (mrow[(size_t)q * KV] == 0) ? 0.f : exp2f(sc[r]*LOG2E);
            pv4[r] = f2bf(p);
            lloc[r] += p;
        }
        *(us4*)(void*)&P[(bh*KV + krow)*QL + g*4] = pv4;
    }

    // sum l over the 16 c-lanes, then across waves
    #pragma unroll
    for (int r = 0; r < 4; r++) {
        float l = lloc[r];
        #pragma unroll
        for (int mm = 1; mm < 16; mm <<= 1) l += __shfl_xor(l, mm);
        if (c == 0) smL[wv][g*4 + r] = l;
    }
    __syncthreads();
    if (t < 16) {
        float L = 0.f;
        #pragma unroll
        for (int w = 0; w < 4; w++) L += smL[w][t];
        statsL[(bh*KCA + kc)*QL + t] = L;
    }
}

// B: V-copy fused with PV. grid (NH*2, BS, KCB), 256 threads.
// Block owns a 64-dim half of head h over BROWS k-rows: copies V slice,
// stages V (bf16) + P in LDS, accumulates O, writes normalized partials.
__global__ __launch_bounds__(256) void vcopy_pv(
    const float* __restrict__ vcache, const __hip_bfloat16* __restrict__ Pbuf,
    const float* __restrict__ statsL,
    float* __restrict__ vout, float* __restrict__ awsP)
{
    int hd = blockIdx.x; int h = hd >> 1, half = hd & 1;
    int b = blockIdx.y, kc = blockIdx.z;
    int t = threadIdx.x;
    size_t bKV = (size_t)b * KV;
    size_t bh  = (size_t)b * NH + h;
    const unsigned short* P = (const unsigned short*)Pbuf;

    __shared__ float smLinv[16];
    __shared__ __align__(16) unsigned short Vl[64*72];  // 64 rows x 64 dims, pad to 72
    __shared__ __align__(16) float Pl[16*68];           // 16 q x 64 k, pad to 68

    if (t < 16) {
        float L = 0.f;
        #pragma unroll
        for (int c4 = 0; c4 < KCA; c4++)
            L += statsL[(bh*KCA + c4)*QL + t];
        smLinv[t] = 1.0f / L;
    }
    __syncthreads();

    int q = t >> 4, dc = t & 15;
    int srow = t >> 2;                 // staging row 0..63
    int vseg = (t & 3) * 16;           // 16-float staging segment within 64 dims
    int pq0  = (t & 3) * 4;            // staging q quarter

    float O[4] = {0.f,0.f,0.f,0.f};

    for (int kt = 0; kt < 16; kt++) {
        int k0 = kc*BROWS + kt*64;
        __syncthreads();
        // ---- stage P (read bf16 exp values directly) ----
        {
            int krow = k0 + srow;
            us4 sv = *(const us4*)(const void*)&P[(bh*KV + krow)*QL + pq0];
            #pragma unroll
            for (int j = 0; j < 4; j++)
                Pl[(pq0+j)*68 + srow] = bf2f(sv[j]);
        }
        // ---- stage V (copy + bf16 to LDS) ----
        {
            int vrow = k0 + srow;
            bool cpy = (vrow < SPLICE);
            const float* src = (cpy ? vcache : vout) + (bKV + vrow)*DM + h*DK + half*64 + vseg;
            float4 v0 = *(const float4*)(src);
            float4 v1 = *(const float4*)(src + 4);
            float4 v2 = *(const float4*)(src + 8);
            float4 v3 = *(const float4*)(src + 12);
            if (cpy) {
                float* dst = vout + (bKV + vrow)*DM + h*DK + half*64 + vseg;
                *(float4*)(dst)      = v0;
                *(float4*)(dst + 4)  = v1;
                *(float4*)(dst + 8)  = v2;
                *(float4*)(dst + 12) = v3;
            }
            us8 p0 = { f2bf(v0.x), f2bf(v0.y), f2bf(v0.z), f2bf(v0.w),
                       f2bf(v1.x), f2bf(v1.y), f2bf(v1.z), f2bf(v1.w) };
            us8 p1 = { f2bf(v2.x), f2bf(v2.y), f2bf(v2.z), f2bf(v2.w),
                       f2bf(v3.x), f2bf(v3.y), f2bf(v3.z), f2bf(v3.w) };
            *(us8*)&Vl[srow*72 + vseg]     = p0;
            *(us8*)&Vl[srow*72 + vseg + 8] = p1;
        }
        __syncthreads();
        // ---- O += P * V ----
        #pragma unroll
        for (int kk0 = 0; kk0 < 64; kk0 += 4) {
            float4 pv = *(const float4*)&Pl[q*68 + kk0];
            #pragma unroll
            for (int j = 0; j < 4; j++) {
                us4 vb = *(const us4*)(const void*)&Vl[(kk0+j)*72 + dc*4];
                float pj = pv[j];
                O[0] += pj*bf2f(vb[0]); O[1] += pj*bf2f(vb[1]);
                O[2] += pj*bf2f(vb[2]); O[3] += pj*bf2f(vb[3]);
            }
        }
    }

    float inv = smLinv[q];
    float* op = awsP + (size_t)kc * MROWS * DM
              + (size_t)(b*QL + q)*DM + h*DK + half*64 + dc*4;
    float4 ov = {O[0]*inv, O[1]*inv, O[2]*inv, O[3]*inv};
    *(float4*)op = ov;
}

extern "C" void kernel_launch(void* const* d_in, const int* in_sizes, int n_in,
                              void* d_out, int out_size, void* d_ws, size_t ws_size,
                              hipStream_t stream)
{
    (void)in_sizes; (void)n_in; (void)out_size; (void)ws_size;

    const float* x      = (const float*)d_in[0];
    const float* kcache = (const float*)d_in[1];
    const float* vcache = (const float*)d_in[2];
    const int*   mask   = (const int*)  d_in[3];
    const float* Wq     = (const float*)d_in[4];
    const float* bq     = (const float*)d_in[5];
    const float* Wk     = (const float*)d_in[6];
    const float* bk     = (const float*)d_in[7];
    const float* Wv     = (const float*)d_in[8];
    const float* bv     = (const float*)d_in[9];
    const float* Wo     = (const float*)d_in[10];
    const float* bo     = (const float*)d_in[11];

    float* out  = (float*)d_out;
    float* kout = out  + (size_t)MROWS * DM;
    float* vout = kout + (size_t)BS * KV * DM;

    float* qws    = (float*)d_ws;                         // 4 MB
    float* aws0   = qws  + (size_t)MROWS * DM;            // 4 MB (kc=0 partial)
    float* aws1   = aws0 + (size_t)MROWS * DM;            // 4 MB (kc=1 partial)
    float* statsL = aws1 + (size_t)MROWS * DM;            // 128 KB
    __hip_bfloat16* Pbuf = (__hip_bfloat16*)(statsL + (size_t)BS * NH * KCA * QL); // 32 MB

    // 1) QKV projections; K/V rows splice directly into cache outputs
    dim3 gq(DM/128, MROWS/128, 3);
    gemm128<<<gq, 256, 0, stream>>>(x, nullptr,
                                    Wq, Wk, Wv, bq, bk, bv,
                                    qws, kout, vout, 0b110);

    // 2) K-copy + P = exp(scores) + l partials
    dim3 ga(NH, BS, KCA);
    kcopy_p<<<ga, 256, 0, stream>>>(qws, kcache, mask, kout, Pbuf, statsL);

    // 3) V-copy + PV partials (kc selects partial buffer inside)
    dim3 gb(NH*2, BS, KCB);
    vcopy_pv<<<gb, 256, 0, stream>>>(vcache, Pbuf, statsL, vout, aws0);

    // 4) output projection, summing the two PV partial buffers
    dim3 go(DM/128, MROWS/128, 1);
    gemm128<<<go, 256, 0, stream>>>(aws0, aws1,
                                    Wo, Wo, Wo, bo, bo, bo,
                                    out, out, out, 0);
}

// Round 8
// 634.732 us; speedup vs baseline: 1.1745x; 1.0848x over previous
//
#include <hip/hip_runtime.h>
#include <hip/hip_bf16.h>

#define BS 32
#define QL 16
#define KV 2048
#define NH 16
#define DK 128
#define DM 2048
#define MROWS (BS*QL)   // 512
#define KCA 4           // kernel-A k-chunks (512 rows each)
#define AROWS (KV/KCA)
#define KCB 2           // kernel-B k-chunks (1024 rows each)
#define BROWS (KV/KCB)
#define SPLICE (KV-QL)  // 2032

#define SCALE 0.08838834764831845f  // 1/sqrt(128)
#define LOG2E 1.4426950408889634f

typedef __bf16 bf16x8 __attribute__((ext_vector_type(8)));
typedef float f32x4 __attribute__((ext_vector_type(4)));
typedef unsigned short us8 __attribute__((ext_vector_type(8)));
typedef unsigned short us4 __attribute__((ext_vector_type(4)));

__device__ inline unsigned short f2bf(float f){
    unsigned u = __builtin_bit_cast(unsigned, f);
    u += 0x7fffu + ((u >> 16) & 1u);
    return (unsigned short)(u >> 16);
}
__device__ inline float bf2f(unsigned short u){
    unsigned x = ((unsigned)u) << 16;
    return __builtin_bit_cast(float, x);
}

// C[m][n] = sum_k (A0(+A1))[m][k] * W[n][k] + bias[n], 64x64 tiles.
__global__ __launch_bounds__(256) void gemm_bt(
    const float* __restrict__ A0p, const float* __restrict__ A1p,
    const float* __restrict__ W0, const float* __restrict__ W1, const float* __restrict__ W2,
    const float* __restrict__ b0, const float* __restrict__ b1, const float* __restrict__ b2,
    float* __restrict__ C0, float* __restrict__ C1, float* __restrict__ C2,
    int spliceMask)
{
    int z = blockIdx.z;
    const float* W    = (z==0)?W0:(z==1)?W1:W2;
    const float* bias = (z==0)?b0:(z==1)?b1:b2;
    float*       C    = (z==0)?C0:(z==1)?C1:C2;
    int spl = (spliceMask >> z) & 1;

    const int K = DM, N = DM;
    int mBase = blockIdx.x * 64, nBase = blockIdx.y * 64;

    __shared__ __align__(16) unsigned short As[64*40];
    __shared__ __align__(16) unsigned short Bs[64*40];

    int t = threadIdx.x;
    int wv = t >> 6, lane = t & 63;
    int row = t >> 2, seg = (t & 3) * 8;
    int g = lane >> 4, c = lane & 15;

    f32x4 acc[4] = {{0,0,0,0},{0,0,0,0},{0,0,0,0},{0,0,0,0}};

    for (int k0 = 0; k0 < K; k0 += 32) {
        __syncthreads();
        {
            size_t off = (size_t)(mBase + row) * K + k0 + seg;
            float4 a0 = *(const float4*)(A0p + off), a1 = *(const float4*)(A0p + off + 4);
            if (A1p) {
                float4 c0 = *(const float4*)(A1p + off), c1 = *(const float4*)(A1p + off + 4);
                a0.x+=c0.x; a0.y+=c0.y; a0.z+=c0.z; a0.w+=c0.w;
                a1.x+=c1.x; a1.y+=c1.y; a1.z+=c1.z; a1.w+=c1.w;
            }
            us8 av = { f2bf(a0.x), f2bf(a0.y), f2bf(a0.z), f2bf(a0.w),
                       f2bf(a1.x), f2bf(a1.y), f2bf(a1.z), f2bf(a1.w) };
            *(us8*)&As[row*40 + seg] = av;
        }
        {
            const float* wp = W + (size_t)(nBase + row) * K + k0 + seg;
            float4 w0v = *(const float4*)wp, w1v = *(const float4*)(wp + 4);
            us8 wv8 = { f2bf(w0v.x), f2bf(w0v.y), f2bf(w0v.z), f2bf(w0v.w),
                        f2bf(w1v.x), f2bf(w1v.y), f2bf(w1v.z), f2bf(w1v.w) };
            *(us8*)&Bs[row*40 + seg] = wv8;
        }
        __syncthreads();

        bf16x8 af = __builtin_bit_cast(bf16x8, *(us8*)&As[(wv*16 + c)*40 + g*8]);
        #pragma unroll
        for (int j = 0; j < 4; j++) {
            bf16x8 bf = __builtin_bit_cast(bf16x8, *(us8*)&Bs[(j*16 + c)*40 + g*8]);
            acc[j] = __builtin_amdgcn_mfma_f32_16x16x32_bf16(af, bf, acc[j], 0, 0, 0);
        }
    }

    #pragma unroll
    for (int j = 0; j < 4; j++) {
        int n = nBase + j*16 + c;
        float bb = bias[n];
        #pragma unroll
        for (int r = 0; r < 4; r++) {
            int m = mBase + wv*16 + g*4 + r;
            size_t rowoff = spl ? ((size_t)(m >> 4) * KV + SPLICE + (m & 15)) * (size_t)N
                                : (size_t)m * (size_t)N;
            C[rowoff + n] = acc[j][r] + bb;
        }
    }
}

// A: K-copy fused with QK^T; max-free softmax: stores P = exp(s) bf16 + l sums.
// grid (NH, BS, KCA), 256 threads (4 waves, 8 tiles of 16 rows each).
__global__ __launch_bounds__(256) void kcopy_p(
    const float* __restrict__ qws, const float* __restrict__ kcache,
    const int* __restrict__ mask,
    float* __restrict__ kout, __hip_bfloat16* __restrict__ Pbuf,
    float* __restrict__ statsL)
{
    int h = blockIdx.x, b = blockIdx.y, kc = blockIdx.z;
    int t = threadIdx.x, wv = t >> 6, lane = t & 63;
    int g = lane >> 4, c = lane & 15;
    size_t bKV = (size_t)b * KV;
    size_t bh  = (size_t)b * NH + h;
    unsigned short* P = (unsigned short*)Pbuf;

    __shared__ float smL[4][16];

    // Q A-fragments for head h (scaled, bf16); constant over the loop
    bf16x8 af[4];
    {
        const float* qp = qws + (size_t)(b*QL + c) * DM + h*DK + g*8;
        #pragma unroll
        for (int ks = 0; ks < 4; ks++) {
            float4 q0 = *(const float4*)(qp + ks*32);
            float4 q1 = *(const float4*)(qp + ks*32 + 4);
            us8 qv = { f2bf(q0.x*SCALE), f2bf(q0.y*SCALE), f2bf(q0.z*SCALE), f2bf(q0.w*SCALE),
                       f2bf(q1.x*SCALE), f2bf(q1.y*SCALE), f2bf(q1.z*SCALE), f2bf(q1.w*SCALE) };
            af[ks] = __builtin_bit_cast(bf16x8, qv);
        }
    }

    float lloc[4] = {0.f,0.f,0.f,0.f};

    for (int i = 0; i < 8; i++) {
        int n0 = kc*AROWS + (i*4 + wv)*16;
        int krow = n0 + c;
        bool spl = (n0 >= SPLICE);   // tile-uniform: only the last tile
        const float* src = (spl ? kout : kcache) + (bKV + krow)*DM + h*DK + g*8;

        float4 kvv[8];
        #pragma unroll
        for (int ks = 0; ks < 4; ks++) {
            kvv[2*ks]   = *(const float4*)(src + ks*32);
            kvv[2*ks+1] = *(const float4*)(src + ks*32 + 4);
        }
        if (!spl) {
            float* dst = kout + (bKV + krow)*DM + h*DK + g*8;
            #pragma unroll
            for (int ks = 0; ks < 4; ks++) {
                *(float4*)(dst + ks*32)     = kvv[2*ks];
                *(float4*)(dst + ks*32 + 4) = kvv[2*ks+1];
            }
        }
        f32x4 sc = {0,0,0,0};
        #pragma unroll
        for (int ks = 0; ks < 4; ks++) {
            float4 k0 = kvv[2*ks], k1 = kvv[2*ks+1];
            us8 kb = { f2bf(k0.x), f2bf(k0.y), f2bf(k0.z), f2bf(k0.w),
                       f2bf(k1.x), f2bf(k1.y), f2bf(k1.z), f2bf(k1.w) };
            sc = __builtin_amdgcn_mfma_f32_16x16x32_bf16(af[ks],
                    __builtin_bit_cast(bf16x8, kb), sc, 0, 0, 0);
        }
        // max-free: p = exp(s) (or 0 if masked); accumulate l; store P bf16
        const int* mrow = mask + (size_t)b * QL * KV + krow;
        us4 pv4;
        #pragma unroll
        for (int r = 0; r < 4; r++) {
            int q = g*4 + r;
            float p = (mrow[(size_t)q * KV] == 0) ? 0.f : exp2f(sc[r]*LOG2E);
            pv4[r] = f2bf(p);
            lloc[r] += p;
        }
        *(us4*)(void*)&P[(bh*KV + krow)*QL + g*4] = pv4;
    }

    // sum l over the 16 c-lanes, then across waves
    #pragma unroll
    for (int r = 0; r < 4; r++) {
        float l = lloc[r];
        #pragma unroll
        for (int mm = 1; mm < 16; mm <<= 1) l += __shfl_xor(l, mm);
        if (c == 0) smL[wv][g*4 + r] = l;
    }
    __syncthreads();
    if (t < 16) {
        float L = 0.f;
        #pragma unroll
        for (int w = 0; w < 4; w++) L += smL[w][t];
        statsL[(bh*KCA + kc)*QL + t] = L;
    }
}

// B: V-copy fused with PV. grid (NH*2, BS, KCB), 256 threads.
// Block owns a 64-dim half of head h over BROWS k-rows: copies V slice,
// stages V (bf16) + P in LDS, accumulates O, writes normalized partials.
__global__ __launch_bounds__(256) void vcopy_pv(
    const float* __restrict__ vcache, const __hip_bfloat16* __restrict__ Pbuf,
    const float* __restrict__ statsL,
    float* __restrict__ vout, float* __restrict__ awsP)
{
    int hd = blockIdx.x; int h = hd >> 1, half = hd & 1;
    int b = blockIdx.y, kc = blockIdx.z;
    int t = threadIdx.x;
    size_t bKV = (size_t)b * KV;
    size_t bh  = (size_t)b * NH + h;
    const unsigned short* P = (const unsigned short*)Pbuf;

    __shared__ float smLinv[16];
    __shared__ __align__(16) unsigned short Vl[64*72];  // 64 rows x 64 dims, pad to 72
    __shared__ __align__(16) float Pl[16*68];           // 16 q x 64 k, pad to 68

    if (t < 16) {
        float L = 0.f;
        #pragma unroll
        for (int c4 = 0; c4 < KCA; c4++)
            L += statsL[(bh*KCA + c4)*QL + t];
        smLinv[t] = 1.0f / L;
    }
    __syncthreads();

    int q = t >> 4, dc = t & 15;
    int srow = t >> 2;                 // staging row 0..63
    int vseg = (t & 3) * 16;           // 16-float staging segment within 64 dims
    int pq0  = (t & 3) * 4;            // staging q quarter

    float O[4] = {0.f,0.f,0.f,0.f};

    for (int kt = 0; kt < 16; kt++) {
        int k0 = kc*BROWS + kt*64;
        __syncthreads();
        // ---- stage P (read bf16 exp values directly) ----
        {
            int krow = k0 + srow;
            us4 sv = *(const us4*)(const void*)&P[(bh*KV + krow)*QL + pq0];
            #pragma unroll
            for (int j = 0; j < 4; j++)
                Pl[(pq0+j)*68 + srow] = bf2f(sv[j]);
        }
        // ---- stage V (copy + bf16 to LDS) ----
        {
            int vrow = k0 + srow;
            bool cpy = (vrow < SPLICE);
            const float* src = (cpy ? vcache : vout) + (bKV + vrow)*DM + h*DK + half*64 + vseg;
            float4 v0 = *(const float4*)(src);
            float4 v1 = *(const float4*)(src + 4);
            float4 v2 = *(const float4*)(src + 8);
            float4 v3 = *(const float4*)(src + 12);
            if (cpy) {
                float* dst = vout + (bKV + vrow)*DM + h*DK + half*64 + vseg;
                *(float4*)(dst)      = v0;
                *(float4*)(dst + 4)  = v1;
                *(float4*)(dst + 8)  = v2;
                *(float4*)(dst + 12) = v3;
            }
            us8 p0 = { f2bf(v0.x), f2bf(v0.y), f2bf(v0.z), f2bf(v0.w),
                       f2bf(v1.x), f2bf(v1.y), f2bf(v1.z), f2bf(v1.w) };
            us8 p1 = { f2bf(v2.x), f2bf(v2.y), f2bf(v2.z), f2bf(v2.w),
                       f2bf(v3.x), f2bf(v3.y), f2bf(v3.z), f2bf(v3.w) };
            *(us8*)&Vl[srow*72 + vseg]     = p0;
            *(us8*)&Vl[srow*72 + vseg + 8] = p1;
        }
        __syncthreads();
        // ---- O += P * V ----
        #pragma unroll
        for (int kk0 = 0; kk0 < 64; kk0 += 4) {
            float4 pv = *(const float4*)&Pl[q*68 + kk0];
            #pragma unroll
            for (int j = 0; j < 4; j++) {
                us4 vb = *(const us4*)(const void*)&Vl[(kk0+j)*72 + dc*4];
                float pj = pv[j];
                O[0] += pj*bf2f(vb[0]); O[1] += pj*bf2f(vb[1]);
                O[2] += pj*bf2f(vb[2]); O[3] += pj*bf2f(vb[3]);
            }
        }
    }

    float inv = smLinv[q];
    float* op = awsP + (size_t)kc * MROWS * DM
              + (size_t)(b*QL + q)*DM + h*DK + half*64 + dc*4;
    float4 ov = {O[0]*inv, O[1]*inv, O[2]*inv, O[3]*inv};
    *(float4*)op = ov;
}

extern "C" void kernel_launch(void* const* d_in, const int* in_sizes, int n_in,
                              void* d_out, int out_size, void* d_ws, size_t ws_size,
                              hipStream_t stream)
{
    (void)in_sizes; (void)n_in; (void)out_size; (void)ws_size;

    const float* x      = (const float*)d_in[0];
    const float* kcache = (const float*)d_in[1];
    const float* vcache = (const float*)d_in[2];
    const int*   mask   = (const int*)  d_in[3];
    const float* Wq     = (const float*)d_in[4];
    const float* bq     = (const float*)d_in[5];
    const float* Wk     = (const float*)d_in[6];
    const float* bk     = (const float*)d_in[7];
    const float* Wv     = (const float*)d_in[8];
    const float* bv     = (const float*)d_in[9];
    const float* Wo     = (const float*)d_in[10];
    const float* bo     = (const float*)d_in[11];

    float* out  = (float*)d_out;
    float* kout = out  + (size_t)MROWS * DM;
    float* vout = kout + (size_t)BS * KV * DM;

    float* qws    = (float*)d_ws;                         // 4 MB
    float* aws0   = qws  + (size_t)MROWS * DM;            // 4 MB (kc=0 partial)
    float* aws1   = aws0 + (size_t)MROWS * DM;            // 4 MB (kc=1 partial)
    float* statsL = aws1 + (size_t)MROWS * DM;            // 128 KB
    __hip_bfloat16* Pbuf = (__hip_bfloat16*)(statsL + (size_t)BS * NH * KCA * QL); // 32 MB

    // 1) QKV projections; K/V rows splice directly into cache outputs
    dim3 gq(MROWS/64, DM/64, 3);
    gemm_bt<<<gq, 256, 0, stream>>>(x, nullptr,
                                    Wq, Wk, Wv, bq, bk, bv,
                                    qws, kout, vout, 0b110);

    // 2) K-copy + P = exp(scores) + l partials
    dim3 ga(NH, BS, KCA);
    kcopy_p<<<ga, 256, 0, stream>>>(qws, kcache, mask, kout, Pbuf, statsL);

    // 3) V-copy + PV partials (kc selects partial buffer inside)
    dim3 gb(NH*2, BS, KCB);
    vcopy_pv<<<gb, 256, 0, stream>>>(vcache, Pbuf, statsL, vout, aws0);

    // 4) output projection, summing the two PV partial buffers
    dim3 go(MROWS/64, DM/64, 1);
    gemm_bt<<<go, 256, 0, stream>>>(aws0, aws1,
                                    Wo, Wo, Wo, bo, bo, bo,
                                    out, out, out, 0);
}

// Round 9
// 567.985 us; speedup vs baseline: 1.3125x; 1.1175x over previous
//
#include <hip/hip_runtime.h>
#include <hip/hip_bf16.h>

#define BS 32
#define QL 16
#define KV 2048
#define NH 16
#define DK 128
#define DM 2048
#define MROWS (BS*QL)   // 512
#define KCA 4           // fused-kernel k-chunks (512 rows each)
#define AROWS (KV/KCA)
#define SPLICE (KV-QL)  // 2032

#define SCALE 0.08838834764831845f  // 1/sqrt(128)
#define LOG2E 1.4426950408889634f

typedef __bf16 bf16x8 __attribute__((ext_vector_type(8)));
typedef float f32x4 __attribute__((ext_vector_type(4)));
typedef unsigned short us8 __attribute__((ext_vector_type(8)));
typedef unsigned short us4 __attribute__((ext_vector_type(4)));

__device__ inline unsigned short f2bf(float f){
    unsigned u = __builtin_bit_cast(unsigned, f);
    u += 0x7fffu + ((u >> 16) & 1u);
    return (unsigned short)(u >> 16);
}
__device__ inline float bf2f(unsigned short u){
    unsigned x = ((unsigned)u) << 16;
    return __builtin_bit_cast(float, x);
}

// C[m][n] = sum_k (A0(+A1))[m][k] * W[n][k] + bias[n], 64x64 tiles.
__global__ __launch_bounds__(256) void gemm_bt(
    const float* __restrict__ A0p, const float* __restrict__ A1p,
    const float* __restrict__ W0, const float* __restrict__ W1, const float* __restrict__ W2,
    const float* __restrict__ b0, const float* __restrict__ b1, const float* __restrict__ b2,
    float* __restrict__ C0, float* __restrict__ C1, float* __restrict__ C2,
    int spliceMask)
{
    int z = blockIdx.z;
    const float* W    = (z==0)?W0:(z==1)?W1:W2;
    const float* bias = (z==0)?b0:(z==1)?b1:b2;
    float*       C    = (z==0)?C0:(z==1)?C1:C2;
    int spl = (spliceMask >> z) & 1;

    const int K = DM, N = DM;
    int mBase = blockIdx.x * 64, nBase = blockIdx.y * 64;

    __shared__ __align__(16) unsigned short As[64*40];
    __shared__ __align__(16) unsigned short Bs[64*40];

    int t = threadIdx.x;
    int wv = t >> 6, lane = t & 63;
    int row = t >> 2, seg = (t & 3) * 8;
    int g = lane >> 4, c = lane & 15;

    f32x4 acc[4] = {{0,0,0,0},{0,0,0,0},{0,0,0,0},{0,0,0,0}};

    for (int k0 = 0; k0 < K; k0 += 32) {
        __syncthreads();
        {
            size_t off = (size_t)(mBase + row) * K + k0 + seg;
            float4 a0 = *(const float4*)(A0p + off), a1 = *(const float4*)(A0p + off + 4);
            if (A1p) {
                float4 c0 = *(const float4*)(A1p + off), c1 = *(const float4*)(A1p + off + 4);
                a0.x+=c0.x; a0.y+=c0.y; a0.z+=c0.z; a0.w+=c0.w;
                a1.x+=c1.x; a1.y+=c1.y; a1.z+=c1.z; a1.w+=c1.w;
            }
            us8 av = { f2bf(a0.x), f2bf(a0.y), f2bf(a0.z), f2bf(a0.w),
                       f2bf(a1.x), f2bf(a1.y), f2bf(a1.z), f2bf(a1.w) };
            *(us8*)&As[row*40 + seg] = av;
        }
        {
            const float* wp = W + (size_t)(nBase + row) * K + k0 + seg;
            float4 w0v = *(const float4*)wp, w1v = *(const float4*)(wp + 4);
            us8 wv8 = { f2bf(w0v.x), f2bf(w0v.y), f2bf(w0v.z), f2bf(w0v.w),
                        f2bf(w1v.x), f2bf(w1v.y), f2bf(w1v.z), f2bf(w1v.w) };
            *(us8*)&Bs[row*40 + seg] = wv8;
        }
        __syncthreads();

        bf16x8 af = __builtin_bit_cast(bf16x8, *(us8*)&As[(wv*16 + c)*40 + g*8]);
        #pragma unroll
        for (int j = 0; j < 4; j++) {
            bf16x8 bf = __builtin_bit_cast(bf16x8, *(us8*)&Bs[(j*16 + c)*40 + g*8]);
            acc[j] = __builtin_amdgcn_mfma_f32_16x16x32_bf16(af, bf, acc[j], 0, 0, 0);
        }
    }

    #pragma unroll
    for (int j = 0; j < 4; j++) {
        int n = nBase + j*16 + c;
        float bb = bias[n];
        #pragma unroll
        for (int r = 0; r < 4; r++) {
            int m = mBase + wv*16 + g*4 + r;
            size_t rowoff = spl ? ((size_t)(m >> 4) * KV + SPLICE + (m & 15)) * (size_t)N
                                : (size_t)m * (size_t)N;
            C[rowoff + n] = acc[j][r] + bb;
        }
    }
}

// Fused K-copy + QK^T + V-copy + PV (max-free softmax).
// grid (NH, BS, KCA), 256 threads = 4 waves; wave handles tiles i*4+wv (16 rows each).
// Swapped QK^T: sc = mfma(K_frag, Q_frag) puts S^T at lane(g,c) = (k=g*4+r, q=c),
// which IS the A-fragment (j=0..3, zero-padded to j=7) of a 16x16x32 PV mfma.
// V staged in LDS at elem (d>>4)*288 + (k>>2)*72 + (k&3)*16 + (d&15) so the PV
// B-fragment is 4 u16 reads at stride 16. O partials (bf16) + L partials to ws.
__global__ __launch_bounds__(256) void fused_kv_attn(
    const float* __restrict__ qws, const float* __restrict__ kcache,
    const float* __restrict__ vcache, const int* __restrict__ mask,
    float* __restrict__ kout, float* __restrict__ vout,
    __hip_bfloat16* __restrict__ Obuf, float* __restrict__ Lbuf)
{
    int h = blockIdx.x, b = blockIdx.y, kc = blockIdx.z;
    int t = threadIdx.x, wv = t >> 6, lane = t & 63;
    int g = lane >> 4, c = lane & 15;
    size_t bKV = (size_t)b * KV;
    size_t bh  = (size_t)b * NH + h;
    unsigned short* Ob = (unsigned short*)Obuf;

    // smem: during main loop = per-wave V tiles (2304 us each, 4x4608 B);
    // after sync = reduction buffer [4][16][132] f32 (33792 B).
    __shared__ __align__(16) unsigned char smem[4*16*132*4];
    unsigned short* Vl = (unsigned short*)smem;
    float* redf = (float*)smem;
    __shared__ float smL[4][16];

    // Q fragments for head h (scaled, bf16): lane c -> q=c, k-slice ks*32+g*8
    bf16x8 af[4];
    {
        const float* qp = qws + (size_t)(b*QL + c) * DM + h*DK + g*8;
        #pragma unroll
        for (int ks = 0; ks < 4; ks++) {
            float4 q0 = *(const float4*)(qp + ks*32);
            float4 q1 = *(const float4*)(qp + ks*32 + 4);
            us8 qv = { f2bf(q0.x*SCALE), f2bf(q0.y*SCALE), f2bf(q0.z*SCALE), f2bf(q0.w*SCALE),
                       f2bf(q1.x*SCALE), f2bf(q1.y*SCALE), f2bf(q1.z*SCALE), f2bf(q1.w*SCALE) };
            af[ks] = __builtin_bit_cast(bf16x8, qv);
        }
    }

    f32x4 Oacc[8];
    #pragma unroll
    for (int nt = 0; nt < 8; nt++) Oacc[nt] = (f32x4){0,0,0,0};
    float lacc = 0.f;

    unsigned short* Vw = Vl + wv*2304;

    for (int i = 0; i < 8; i++) {
        int n0 = kc*AROWS + (i*4 + wv)*16;
        bool spl = (n0 >= SPLICE);   // tile-uniform (16-aligned, SPLICE=2032)

        // ---- K: copy + swapped QK^T (loads ARE the MFMA fragments) ----
        int krow = n0 + c;
        const float* ksrc = (spl ? kout : kcache) + (bKV + krow)*DM + h*DK + g*8;
        float4 kvv[8];
        #pragma unroll
        for (int ks = 0; ks < 4; ks++) {
            kvv[2*ks]   = *(const float4*)(ksrc + ks*32);
            kvv[2*ks+1] = *(const float4*)(ksrc + ks*32 + 4);
        }
        if (!spl) {
            float* kdst = kout + (bKV + krow)*DM + h*DK + g*8;
            #pragma unroll
            for (int ks = 0; ks < 4; ks++) {
                *(float4*)(kdst + ks*32)     = kvv[2*ks];
                *(float4*)(kdst + ks*32 + 4) = kvv[2*ks+1];
            }
        }
        f32x4 sc = {0,0,0,0};
        #pragma unroll
        for (int ks = 0; ks < 4; ks++) {
            float4 k0 = kvv[2*ks], k1 = kvv[2*ks+1];
            us8 kb = { f2bf(k0.x), f2bf(k0.y), f2bf(k0.z), f2bf(k0.w),
                       f2bf(k1.x), f2bf(k1.y), f2bf(k1.z), f2bf(k1.w) };
            // swapped: K as A-operand, Q as B-operand -> D[k][q]
            sc = __builtin_amdgcn_mfma_f32_16x16x32_bf16(
                    __builtin_bit_cast(bf16x8, kb), af[ks], sc, 0, 0, 0);
        }

        // ---- mask + p = exp(s); contiguous int4 mask load (4 consecutive k) ----
        const int4 mv = *(const int4*)(mask + ((size_t)b*QL + c)*KV + n0 + g*4);
        int mi[4] = {mv.x, mv.y, mv.z, mv.w};
        float p[4];
        #pragma unroll
        for (int r = 0; r < 4; r++) {
            p[r] = mi[r] ? exp2f(sc[r]*LOG2E) : 0.f;
            lacc += p[r];
        }
        us8 pa = { f2bf(p[0]), f2bf(p[1]), f2bf(p[2]), f2bf(p[3]), 0, 0, 0, 0 };
        bf16x8 paf = __builtin_bit_cast(bf16x8, pa);

        // ---- V: copy + stage to LDS in PV-fragment layout ----
        #pragma unroll
        for (int f = 0; f < 8; f++) {
            int k  = (f & 1)*8 + (lane >> 3);
            int d0 = ((lane & 7)*4) + (f >> 1)*32;
            size_t off = (bKV + n0 + k)*DM + h*DK + d0;
            const float* vs = (spl ? vout : vcache) + off;
            float4 v = *(const float4*)vs;
            if (!spl) *(float4*)(vout + off) = v;
            int e = (d0 >> 4)*288 + (k >> 2)*72 + (k & 3)*16 + (d0 & 15);
            us4 bv4 = { f2bf(v.x), f2bf(v.y), f2bf(v.z), f2bf(v.w) };
            *(us4*)&Vw[e] = bv4;
        }

        // ---- PV: 8 zero-padded 16x16x32 mfmas (K=16 real) ----
        #pragma unroll
        for (int nt = 0; nt < 8; nt++) {
            const unsigned short* vb = Vw + nt*288 + g*72 + c;
            us8 b8 = { vb[0], vb[16], vb[32], vb[48], 0, 0, 0, 0 };
            Oacc[nt] = __builtin_amdgcn_mfma_f32_16x16x32_bf16(
                          paf, __builtin_bit_cast(bf16x8, b8), Oacc[nt], 0, 0, 0);
        }
    }

    // ---- L reduce: sum over g-groups (k) per q=c ----
    lacc += __shfl_xor(lacc, 16);
    lacc += __shfl_xor(lacc, 32);
    if (lane < 16) smL[wv][lane] = lacc;

    __syncthreads();  // all waves done reading their V tiles; smem becomes redf

    // Oacc[nt][r] = O[q=g*4+r][d=c+nt*16] -> redf[wv][q][d] (132-pad rows)
    #pragma unroll
    for (int nt = 0; nt < 8; nt++)
        #pragma unroll
        for (int r = 0; r < 4; r++)
            redf[wv*2112 + (g*4 + r)*132 + c + nt*16] = Oacc[nt][r];
    __syncthreads();

    // combine 4 wave partials -> bf16 Obuf, L -> Lbuf
    {
        int q = t >> 4, d0 = (t & 15)*8;
        float s[8] = {0,0,0,0,0,0,0,0};
        #pragma unroll
        for (int w = 0; w < 4; w++) {
            float4 x0 = *(const float4*)&redf[w*2112 + q*132 + d0];
            float4 x1 = *(const float4*)&redf[w*2112 + q*132 + d0 + 4];
            s[0]+=x0.x; s[1]+=x0.y; s[2]+=x0.z; s[3]+=x0.w;
            s[4]+=x1.x; s[5]+=x1.y; s[6]+=x1.z; s[7]+=x1.w;
        }
        us8 o = { f2bf(s[0]), f2bf(s[1]), f2bf(s[2]), f2bf(s[3]),
                  f2bf(s[4]), f2bf(s[5]), f2bf(s[6]), f2bf(s[7]) };
        *(us8*)(void*)&Ob[(((size_t)kc*(BS*NH) + bh)*QL + q)*DK + d0] = o;
        if (t < 16)
            Lbuf[(bh*KCA + kc)*QL + t] = smL[0][t] + smL[1][t] + smL[2][t] + smL[3][t];
    }
}

// Normalize + sum the KCA chunk partials into aws (f32). 512 blocks x 256 thr x 8 f.
__global__ __launch_bounds__(256) void attn_combine(
    const __hip_bfloat16* __restrict__ Obuf, const float* __restrict__ Lbuf,
    float* __restrict__ aws)
{
    int idx8 = blockIdx.x * 256 + threadIdx.x;   // unit = 8 floats
    int m = idx8 >> 8;                            // output row (0..511)
    int col = (idx8 & 255) * 8;                   // column (0..2040)
    int b = m >> 4, q = m & 15;
    int h = col >> 7, d0 = col & 127;
    size_t bh = (size_t)b * NH + h;
    const unsigned short* Ob = (const unsigned short*)Obuf;

    float L = 0.f;
    #pragma unroll
    for (int kc = 0; kc < KCA; kc++) L += Lbuf[(bh*KCA + kc)*QL + q];
    float inv = 1.0f / L;

    float s[8] = {0,0,0,0,0,0,0,0};
    #pragma unroll
    for (int kc = 0; kc < KCA; kc++) {
        us8 o = *(const us8*)(const void*)&Ob[(((size_t)kc*(BS*NH) + bh)*QL + q)*DK + d0];
        #pragma unroll
        for (int j = 0; j < 8; j++) s[j] += bf2f(o[j]);
    }
    float* op = aws + (size_t)m * DM + col;
    float4 o0 = {s[0]*inv, s[1]*inv, s[2]*inv, s[3]*inv};
    float4 o1 = {s[4]*inv, s[5]*inv, s[6]*inv, s[7]*inv};
    *(float4*)op = o0;
    *(float4*)(op + 4) = o1;
}

extern "C" void kernel_launch(void* const* d_in, const int* in_sizes, int n_in,
                              void* d_out, int out_size, void* d_ws, size_t ws_size,
                              hipStream_t stream)
{
    (void)in_sizes; (void)n_in; (void)out_size; (void)ws_size;

    const float* x      = (const float*)d_in[0];
    const float* kcache = (const float*)d_in[1];
    const float* vcache = (const float*)d_in[2];
    const int*   mask   = (const int*)  d_in[3];
    const float* Wq     = (const float*)d_in[4];
    const float* bq     = (const float*)d_in[5];
    const float* Wk     = (const float*)d_in[6];
    const float* bk     = (const float*)d_in[7];
    const float* Wv     = (const float*)d_in[8];
    const float* bv     = (const float*)d_in[9];
    const float* Wo     = (const float*)d_in[10];
    const float* bo     = (const float*)d_in[11];

    float* out  = (float*)d_out;
    float* kout = out  + (size_t)MROWS * DM;
    float* vout = kout + (size_t)BS * KV * DM;

    float* qws  = (float*)d_ws;                              // 4 MB
    float* aws  = qws + (size_t)MROWS * DM;                  // 4 MB
    float* Lbuf = aws + (size_t)MROWS * DM;                  // 128 KB
    __hip_bfloat16* Obuf = (__hip_bfloat16*)(Lbuf + (size_t)BS*NH*KCA*QL);  // 8 MB

    // 1) QKV projections; K/V rows splice directly into cache outputs
    dim3 gq(MROWS/64, DM/64, 3);
    gemm_bt<<<gq, 256, 0, stream>>>(x, nullptr,
                                    Wq, Wk, Wv, bq, bk, bv,
                                    qws, kout, vout, 0b110);

    // 2) fused K/V copy + attention partials
    dim3 gf(NH, BS, KCA);
    fused_kv_attn<<<gf, 256, 0, stream>>>(qws, kcache, vcache, mask,
                                          kout, vout, Obuf, Lbuf);

    // 3) normalize + sum chunk partials
    attn_combine<<<512, 256, 0, stream>>>(Obuf, Lbuf, aws);

    // 4) output projection
    dim3 go(MROWS/64, DM/64, 1);
    gemm_bt<<<go, 256, 0, stream>>>(aws, nullptr,
                                    Wo, Wo, Wo, bo, bo, bo,
                                    out, out, out, 0);
}